// Round 1
// baseline (364.385 us; speedup 1.0000x reference)
//
#include <hip/hip_runtime.h>
#include <math.h>

#define N     1024
#define H     16
#define HD    64
#define E     16384
#define LPATH 4
#define SCALE 0.125f

// ------------------------------------------------------------------
// K2: C[e][l][h] = dot(edge_feat[e], edge_weight[l][h]) ; row E = 0
// ------------------------------------------------------------------
__global__ __launch_bounds__(256) void edge_pre_kernel(
    const float* __restrict__ EF, const float* __restrict__ EW, float* __restrict__ C)
{
    __shared__ float ews[64][66];   // padded: bank (2*lh+d)%32 -> 2-way
    __shared__ float ef[16][64];
    const int t = threadIdx.x;
    const int e0 = blockIdx.x * 16;
    #pragma unroll
    for (int i = 0; i < 16; ++i) {
        int idx = t + i * 256;                 // 4096 = L*H*HD
        ews[idx >> 6][idx & 63] = EW[idx];
    }
    #pragma unroll
    for (int i = 0; i < 4; ++i) {
        int idx = t + i * 256;
        int r = idx >> 6, d = idx & 63;
        int e = e0 + r;
        ef[r][d] = (e < E) ? EF[(size_t)e * 64 + d] : 0.f;
    }
    __syncthreads();
    const int lh = t & 63;
    const int rb = t >> 6;
    #pragma unroll
    for (int j = 0; j < 4; ++j) {
        int r = rb * 4 + j;
        int e = e0 + r;
        if (e > E) continue;
        float acc = 0.f;
        if (e < E) {
            #pragma unroll
            for (int d = 0; d < 64; ++d) acc += ef[r][d] * ews[lh][d];
        }
        C[(size_t)e * 64 + lh] = acc;          // e==E -> zeros (pad row)
    }
}

// ------------------------------------------------------------------
// Generic 64x64-tile fp32 GEMM core: Cout[row0+r][col0+c] =
//   sum_k A[row0+r][k]*B[k][col0+c] (+bias[col0+c]); all strides 1024, K=1024
// ------------------------------------------------------------------
__device__ __forceinline__ void gemm64_core(
    const float* __restrict__ A, const float* __restrict__ B,
    const float* __restrict__ bias, float* __restrict__ Cout,
    int row0, int col0)
{
    __shared__ float As[16][68];   // [kk][r] (transposed A tile)
    __shared__ float Bs[16][68];   // [kk][c]
    const int t  = threadIdx.x;
    const int tx = t & 15, ty = t >> 4;
    const int ar = t >> 2, aq = (t & 3) * 4;
    const int bk = t >> 4, bc = (t & 15) * 4;
    float acc[4][4] = {};
    for (int k0 = 0; k0 < 1024; k0 += 16) {
        float4 av = *(const float4*)&A[(size_t)(row0 + ar) * 1024 + k0 + aq];
        float4 bv = *(const float4*)&B[(size_t)(k0 + bk) * 1024 + col0 + bc];
        __syncthreads();
        As[aq + 0][ar] = av.x; As[aq + 1][ar] = av.y;
        As[aq + 2][ar] = av.z; As[aq + 3][ar] = av.w;
        *(float4*)&Bs[bk][bc] = bv;
        __syncthreads();
        #pragma unroll
        for (int kk = 0; kk < 16; ++kk) {
            float4 a4 = *(const float4*)&As[kk][ty * 4];
            float4 b4 = *(const float4*)&Bs[kk][tx * 4];
            float a[4] = {a4.x, a4.y, a4.z, a4.w};
            float b[4] = {b4.x, b4.y, b4.z, b4.w};
            #pragma unroll
            for (int i = 0; i < 4; ++i)
                #pragma unroll
                for (int j = 0; j < 4; ++j) acc[i][j] += a[i] * b[j];
        }
    }
    float4 bb = make_float4(0.f, 0.f, 0.f, 0.f);
    if (bias) bb = *(const float4*)&bias[col0 + tx * 4];
    #pragma unroll
    for (int i = 0; i < 4; ++i) {
        float4 o = make_float4(acc[i][0] + bb.x, acc[i][1] + bb.y,
                               acc[i][2] + bb.z, acc[i][3] + bb.w);
        *(float4*)&Cout[(size_t)(row0 + ty * 4 + i) * 1024 + col0 + tx * 4] = o;
    }
}

// K1: fused QKV projection. grid (48,16): sel = x>>4 picks q/k/v.
__global__ __launch_bounds__(256) void qkv_kernel(
    const float* __restrict__ X,
    const float* __restrict__ Wq, const float* __restrict__ bq,
    const float* __restrict__ Wk, const float* __restrict__ bk,
    const float* __restrict__ Wv, const float* __restrict__ bv,
    float* Q, float* K, float* V)
{
    const int sel  = blockIdx.x >> 4;
    const int col0 = (blockIdx.x & 15) * 64;
    const int row0 = blockIdx.y * 64;
    const float* B    = (sel == 0) ? Wq : (sel == 1) ? Wk : Wv;
    const float* bias = (sel == 0) ? bq : (sel == 1) ? bk : bv;
    float*       O    = (sel == 0) ? Q  : (sel == 1) ? K  : V;
    gemm64_core(X, B, bias, O, row0, col0);
}

// K6: out = attnout @ Wo + bo. grid (16,16)
__global__ __launch_bounds__(256) void out_proj_kernel(
    const float* __restrict__ A, const float* __restrict__ Wo,
    const float* __restrict__ bo, float* __restrict__ O)
{
    gemm64_core(A, Wo, bo, O, blockIdx.y * 64, blockIdx.x * 64);
}

// K5: PV. grid (16 h, 16 ntile): attnout[n][h*64+d] = sum_m attn[h][n][m]*V[m][h*64+d]
__global__ __launch_bounds__(256) void pv_kernel(
    const float* __restrict__ attn, const float* __restrict__ V, float* __restrict__ O)
{
    gemm64_core(attn + ((size_t)blockIdx.x << 20), V, nullptr, O,
                blockIdx.y * 64, blockIdx.x * 64);
}

// ------------------------------------------------------------------
// K3: per-head QK^T. grid (8 mtile, 8 ntile, 16 h), 128x128 tile, 8x8/thread
// score[h][n][m] = SCALE * sum_d Q[n][h*64+d]*K[m][h*64+d]
// ------------------------------------------------------------------
__global__ __launch_bounds__(256) void qk_score_kernel(
    const float* __restrict__ Q, const float* __restrict__ K, float* __restrict__ S)
{
    const int t  = threadIdx.x, tx = t & 15, ty = t >> 4;
    const int m0 = blockIdx.x * 128, n0 = blockIdx.y * 128, h = blockIdx.z;
    __shared__ float Qs[8][136];   // [kk][n]
    __shared__ float Ks[8][136];   // [kk][m]
    float acc[8][8] = {};
    const int lr = t >> 1, lq = (t & 1) * 4;
    for (int k0 = 0; k0 < 64; k0 += 8) {
        float4 qv = *(const float4*)&Q[(size_t)(n0 + lr) * 1024 + h * 64 + k0 + lq];
        float4 kv = *(const float4*)&K[(size_t)(m0 + lr) * 1024 + h * 64 + k0 + lq];
        __syncthreads();
        Qs[lq + 0][lr] = qv.x; Qs[lq + 1][lr] = qv.y;
        Qs[lq + 2][lr] = qv.z; Qs[lq + 3][lr] = qv.w;
        Ks[lq + 0][lr] = kv.x; Ks[lq + 1][lr] = kv.y;
        Ks[lq + 2][lr] = kv.z; Ks[lq + 3][lr] = kv.w;
        __syncthreads();
        #pragma unroll
        for (int kk = 0; kk < 8; ++kk) {
            float4 a0 = *(const float4*)&Qs[kk][ty * 4];
            float4 a1 = *(const float4*)&Qs[kk][ty * 4 + 64];
            float4 b0 = *(const float4*)&Ks[kk][tx * 4];
            float4 b1 = *(const float4*)&Ks[kk][tx * 4 + 64];
            float a[8] = {a0.x, a0.y, a0.z, a0.w, a1.x, a1.y, a1.z, a1.w};
            float b[8] = {b0.x, b0.y, b0.z, b0.w, b1.x, b1.y, b1.z, b1.w};
            #pragma unroll
            for (int i = 0; i < 8; ++i)
                #pragma unroll
                for (int j = 0; j < 8; ++j) acc[i][j] += a[i] * b[j];
        }
    }
    float* So = S + ((size_t)h << 20);
    #pragma unroll
    for (int i = 0; i < 8; ++i) {
        int r = n0 + ty * 4 + (i & 3) + (i >> 2) * 64;
        #pragma unroll
        for (int jh = 0; jh < 2; ++jh) {
            float4 o = make_float4(acc[i][jh * 4 + 0] * SCALE, acc[i][jh * 4 + 1] * SCALE,
                                   acc[i][jh * 4 + 2] * SCALE, acc[i][jh * 4 + 3] * SCALE);
            *(float4*)&So[(size_t)r * 1024 + m0 + tx * 4 + jh * 64] = o;
        }
    }
}

// ------------------------------------------------------------------
// K4: bias (spatial + edge enc) + mask + softmax over m, in-place on score.
// grid (1024): one block per query row n. Heads processed 4 at a time so the
// C gathers are 16B vector loads shared across the head chunk.
// ------------------------------------------------------------------
__global__ __launch_bounds__(256) void bias_softmax_kernel(
    const int* __restrict__ SD, const int* __restrict__ SP,
    const float* __restrict__ C, const float* __restrict__ STBL,
    float* __restrict__ S)
{
    __shared__ int   sdl[N];
    __shared__ int   spl[N * 4];
    __shared__ float stbl[80];
    __shared__ float bias[4][N];
    __shared__ float red[4];
    const int t = threadIdx.x;
    const int n = blockIdx.x;
    #pragma unroll
    for (int k = 0; k < 4; ++k) sdl[t + k * 256] = SD[(size_t)n * N + t + k * 256];
    #pragma unroll
    for (int k = 0; k < 4; ++k) {
        int4 v = *(const int4*)&SP[((size_t)n * N + t + k * 256) * 4];
        *(int4*)&spl[(t + k * 256) * 4] = v;
    }
    if (t < 80) stbl[t] = STBL[t];
    __syncthreads();

    for (int hc = 0; hc < H; hc += 4) {
        __syncthreads();   // protect bias[] reuse across chunks
        #pragma unroll
        for (int k = 0; k < 4; ++k) {
            int m   = t + k * 256;
            int sdv = sdl[m];
            int cl  = sdv > LPATH ? LPATH : (sdv < 0 ? 0 : sdv);
            float4 b  = *(const float4*)&stbl[cl * 16 + hc];
            int4   e4 = *(const int4*)&spl[m * 4];
            float4 c0 = *(const float4*)&C[(size_t)e4.x * 64 +  0 + hc];
            float4 c1 = *(const float4*)&C[(size_t)e4.y * 64 + 16 + hc];
            float4 c2 = *(const float4*)&C[(size_t)e4.z * 64 + 32 + hc];
            float4 c3 = *(const float4*)&C[(size_t)e4.w * 64 + 48 + hc];
            b.x += c0.x + c1.x + c2.x + c3.x;
            b.y += c0.y + c1.y + c2.y + c3.y;
            b.z += c0.z + c1.z + c2.z + c3.z;
            b.w += c0.w + c1.w + c2.w + c3.w;
            bias[0][m] = b.x; bias[1][m] = b.y; bias[2][m] = b.z; bias[3][m] = b.w;
        }
        __syncthreads();
        for (int hh = 0; hh < 4; ++hh) {
            const int h = hc + hh;
            float* srow = S + (((size_t)h << 10) + n) * 1024;   // h*N*N + n*N
            float v[4];
            float lmax = -INFINITY;
            #pragma unroll
            for (int k = 0; k < 4; ++k) {
                int m = t + k * 256;
                float x = (sdl[m] <= 0) ? -INFINITY : srow[m] + bias[hh][m];
                v[k] = x;
                lmax = fmaxf(lmax, x);
            }
            #pragma unroll
            for (int o = 32; o; o >>= 1) lmax = fmaxf(lmax, __shfl_xor(lmax, o));
            if ((t & 63) == 0) red[t >> 6] = lmax;
            __syncthreads();
            lmax = fmaxf(fmaxf(red[0], red[1]), fmaxf(red[2], red[3]));
            __syncthreads();
            float lsum = 0.f;
            #pragma unroll
            for (int k = 0; k < 4; ++k) { v[k] = __expf(v[k] - lmax); lsum += v[k]; }
            #pragma unroll
            for (int o = 32; o; o >>= 1) lsum += __shfl_xor(lsum, o);
            if ((t & 63) == 0) red[t >> 6] = lsum;
            __syncthreads();
            lsum = red[0] + red[1] + red[2] + red[3];
            __syncthreads();
            float inv = 1.f / lsum;
            #pragma unroll
            for (int k = 0; k < 4; ++k) srow[t + k * 256] = v[k] * inv;
        }
    }
}

// ------------------------------------------------------------------
extern "C" void kernel_launch(void* const* d_in, const int* in_sizes, int n_in,
                              void* d_out, int out_size, void* d_ws, size_t ws_size,
                              hipStream_t stream)
{
    const float* node_feat = (const float*)d_in[0];
    const float* edge_feat = (const float*)d_in[1];
    // d_in[2] distances: unused by reference
    const int*   sd        = (const int*)d_in[3];
    const int*   sp        = (const int*)d_in[4];
    // d_in[5] edge_type: unused by reference
    const float* Wq = (const float*)d_in[6];
    const float* bq = (const float*)d_in[7];
    const float* Wk = (const float*)d_in[8];
    const float* bk = (const float*)d_in[9];
    const float* Wv = (const float*)d_in[10];
    const float* bv = (const float*)d_in[11];
    const float* Wo = (const float*)d_in[12];
    const float* bo = (const float*)d_in[13];
    const float* spatial = (const float*)d_in[14];
    const float* ew      = (const float*)d_in[15];
    float* out = (float*)d_out;

    float* ws      = (float*)d_ws;
    float* Q       = ws;                            // 1M floats
    float* Kb      = Q + (size_t)N * 1024;          // 1M
    float* Vb      = Kb + (size_t)N * 1024;         // 1M
    float* C       = Vb + (size_t)N * 1024;         // (E+1)*64 = 1,048,640
    float* score   = C + (size_t)(E + 1) * 64;      // 16M (attn in-place)
    float* attnout = score + (size_t)H * N * N;     // 1M

    edge_pre_kernel<<<dim3(E / 16 + 1), 256, 0, stream>>>(edge_feat, ew, C);
    qkv_kernel<<<dim3(48, 16), 256, 0, stream>>>(node_feat, Wq, bq, Wk, bk, Wv, bv,
                                                 Q, Kb, Vb);
    qk_score_kernel<<<dim3(8, 8, 16), 256, 0, stream>>>(Q, Kb, score);
    bias_softmax_kernel<<<dim3(1024), 256, 0, stream>>>(sd, sp, C, spatial, score);
    pv_kernel<<<dim3(16, 16), 256, 0, stream>>>(score, Vb, attnout);
    out_proj_kernel<<<dim3(16, 16), 256, 0, stream>>>(attnout, Wo, bo, out);
}

// Round 2
// 205.479 us; speedup vs baseline: 1.7733x; 1.7733x over previous
//
#include <hip/hip_runtime.h>
#include <math.h>

#define N_    1024
#define H_    16
#define E_    16384
#define SCALE 0.125f

typedef unsigned short u16;
typedef short  short8v __attribute__((ext_vector_type(8)));
typedef float  f32x4   __attribute__((ext_vector_type(4)));
typedef u16    u16x4   __attribute__((ext_vector_type(4)));
typedef u16    u16x8   __attribute__((ext_vector_type(8)));

__device__ __forceinline__ u16 f2bf(float f) {
    union { float f; unsigned u; } v; v.f = f;
    unsigned r = v.u + 0x7fffu + ((v.u >> 16) & 1u);
    return (u16)(r >> 16);
}

// ---------------------------------------------------------------
// staging: global(bf16, row-major, ld=ldr) -> LDS tile [rows][64]
// with XOR slot swizzle applied on the GLOBAL source (linear LDS
// dest required by global_load_lds). 16B/lane, U64 wave-chunks.
// ---------------------------------------------------------------
template<int U64>
__device__ __forceinline__ void stage_bt(const u16* __restrict__ g, int ldr,
                                         u16* s, int tid)
{
    const int l = tid & 63, w = tid >> 6;
    for (int c = w; c < U64; c += 4) {
        int o16 = (c << 6) + l;          // 16B-unit index in tile
        int row = o16 >> 3;
        int ss  = (o16 & 7) ^ (row & 7); // source slot (inverse swizzle)
        const u16* gp = g + (size_t)row * ldr + (ss << 3);
        u16* lp = s + (c << 9);          // wave-uniform base; HW adds lane*16
        __builtin_amdgcn_global_load_lds(
            (const __attribute__((address_space(1))) void*)gp,
            (__attribute__((address_space(3))) void*)lp, 16, 0, 0);
    }
}

__device__ __forceinline__ short8v frag_read(const u16* s, int row, int slot) {
    return *(const short8v*)(s + row * 64 + ((slot ^ (row & 7)) << 3));
}

// ---------------------------------------------------------------
// bf16 GEMM-BT core: A[M][K] bf16 (lda), Bt[N][K] bf16 (ldb).
// Block tile 128 x NT, 4 waves (2x2), BK=64, mfma 16x16x32.
// ---------------------------------------------------------------
template<int NT>
__device__ __forceinline__ void gemm_bt_core(
    const u16* __restrict__ At, int lda,
    const u16* __restrict__ Bt, int ldb,
    int K, u16* As, u16* Bs, f32x4 (&acc)[4][NT/32], int tid)
{
    const int l  = tid & 63;
    const int wm = tid >> 7, wn = (tid >> 6) & 1;
    const int lr = l & 15,   lk = l >> 4;
    for (int k0 = 0; k0 < K; k0 += 64) {
        if (k0) __syncthreads();
        stage_bt<16>(At + k0, lda, As, tid);
        stage_bt<NT/8>(Bt + k0, ldb, Bs, tid);
        __syncthreads();
        #pragma unroll
        for (int s = 0; s < 2; ++s) {
            short8v af[4], bfv[NT/32];
            #pragma unroll
            for (int i = 0; i < 4; ++i)
                af[i] = frag_read(As, wm*64 + i*16 + lr, s*4 + lk);
            #pragma unroll
            for (int j = 0; j < NT/32; ++j)
                bfv[j] = frag_read(Bs, wn*(NT/2) + j*16 + lr, s*4 + lk);
            #pragma unroll
            for (int i = 0; i < 4; ++i)
                #pragma unroll
                for (int j = 0; j < NT/32; ++j)
                    asm("v_mfma_f32_16x16x32_bf16 %0, %1, %2, %0"
                        : "+v"(acc[i][j]) : "v"(af[i]), "v"(bfv[j]));
        }
    }
    __syncthreads();   // also covers MFMA->VALU read hazard before epilogue
}

// ---------------------------------------------------------------
// converts
// ---------------------------------------------------------------
__global__ __launch_bounds__(256) void conv_x(const float* __restrict__ X,
                                              u16* __restrict__ Xb)
{
    size_t i = (size_t)blockIdx.x * 256 + threadIdx.x;
    float4 a = ((const float4*)X)[2*i], b = ((const float4*)X)[2*i + 1];
    u16x8 o;
    o[0]=f2bf(a.x); o[1]=f2bf(a.y); o[2]=f2bf(a.z); o[3]=f2bf(a.w);
    o[4]=f2bf(b.x); o[5]=f2bf(b.y); o[6]=f2bf(b.z); o[7]=f2bf(b.w);
    *(u16x8*)&Xb[8*i] = o;
}

__global__ __launch_bounds__(256) void conv_wt(
    const float* __restrict__ Wq, const float* __restrict__ Wk,
    const float* __restrict__ Wv, const float* __restrict__ Wo,
    u16* __restrict__ Wt)
{
    __shared__ u16 tile[64][65];
    const int t = threadIdx.x;
    const int n0 = blockIdx.x*64, k0 = blockIdx.y*64, mz = blockIdx.z;
    const float* W = mz==0 ? Wq : mz==1 ? Wk : mz==2 ? Wv : Wo;
    u16* Wd = Wt + (size_t)mz * 1024 * 1024;
    #pragma unroll
    for (int p = 0; p < 4; ++p) {
        int r = p*16 + (t>>4), c = (t&15)*4;
        float4 v = *(const float4*)&W[(size_t)(k0+r)*1024 + n0 + c];
        tile[c+0][r]=f2bf(v.x); tile[c+1][r]=f2bf(v.y);
        tile[c+2][r]=f2bf(v.z); tile[c+3][r]=f2bf(v.w);
    }
    __syncthreads();
    #pragma unroll
    for (int p = 0; p < 4; ++p) {
        int nr = p*16 + (t>>4), kc = (t&15)*4;
        u16x4 o = { tile[nr][kc], tile[nr][kc+1], tile[nr][kc+2], tile[nr][kc+3] };
        *(u16x4*)&Wd[(size_t)(n0+nr)*1024 + k0 + kc] = o;
    }
}

__global__ __launch_bounds__(256) void transpose_v(const u16* __restrict__ Vb,
                                                   u16* __restrict__ Vt)
{
    __shared__ u16 tile[64][65];
    const int t = threadIdx.x;
    const int c0 = blockIdx.x*64, r0 = blockIdx.y*64;
    #pragma unroll
    for (int p = 0; p < 4; ++p) {
        int r = p*16 + (t>>4), c = (t&15)*4;
        u16x4 v = *(const u16x4*)&Vb[(size_t)(r0+r)*1024 + c0 + c];
        tile[c+0][r]=v[0]; tile[c+1][r]=v[1]; tile[c+2][r]=v[2]; tile[c+3][r]=v[3];
    }
    __syncthreads();
    #pragma unroll
    for (int p = 0; p < 4; ++p) {
        int cr = p*16 + (t>>4), rc = (t&15)*4;
        u16x4 o = { tile[cr][rc], tile[cr][rc+1], tile[cr][rc+2], tile[cr][rc+3] };
        *(u16x4*)&Vt[(size_t)(c0+cr)*1024 + r0 + rc] = o;
    }
}

// ---------------------------------------------------------------
// C[e][l][h] = dot(edge_feat[e], edge_weight[l][h]) ; row E = 0
// ---------------------------------------------------------------
__global__ __launch_bounds__(256) void edge_pre_kernel(
    const float* __restrict__ EF, const float* __restrict__ EW, float* __restrict__ C)
{
    __shared__ float ews[64][66];
    __shared__ float ef[16][64];
    const int t = threadIdx.x;
    const int e0 = blockIdx.x * 16;
    #pragma unroll
    for (int i = 0; i < 16; ++i) {
        int idx = t + i * 256;
        ews[idx >> 6][idx & 63] = EW[idx];
    }
    #pragma unroll
    for (int i = 0; i < 4; ++i) {
        int idx = t + i * 256;
        int r = idx >> 6, d = idx & 63;
        int e = e0 + r;
        ef[r][d] = (e < E_) ? EF[(size_t)e * 64 + d] : 0.f;
    }
    __syncthreads();
    const int lh = t & 63;
    const int rb = t >> 6;
    #pragma unroll
    for (int j = 0; j < 4; ++j) {
        int r = rb * 4 + j;
        int e = e0 + r;
        if (e > E_) continue;
        float acc = 0.f;
        if (e < E_) {
            #pragma unroll
            for (int d = 0; d < 64; ++d) acc += ef[r][d] * ews[lh][d];
        }
        C[(size_t)e * 64 + lh] = acc;
    }
}

// ---------------------------------------------------------------
// GEMM kernels
// ---------------------------------------------------------------
__global__ __launch_bounds__(256) void qkv_gemm(
    const u16* __restrict__ Xb, const u16* __restrict__ Wt,
    const float* __restrict__ bq, const float* __restrict__ bk,
    const float* __restrict__ bv,
    u16* __restrict__ Qb, u16* __restrict__ Kb, u16* __restrict__ Vb)
{
    __shared__ u16 As[128*64], Bs[128*64];
    const int tid = threadIdx.x;
    const int col0 = blockIdx.x * 128, row0 = blockIdx.y * 128;
    f32x4 acc[4][4] = {};
    gemm_bt_core<128>(Xb + (size_t)row0*1024, 1024,
                      Wt + (size_t)col0*1024, 1024, 1024, As, Bs, acc, tid);
    const int l = tid & 63, wm = tid>>7, wn = (tid>>6)&1, lr = l&15, lk = l>>4;
    const int sel = col0 >> 10;
    const float* bias = sel==0 ? bq : sel==1 ? bk : bv;
    u16* O = sel==0 ? Qb : sel==1 ? Kb : Vb;
    const int cbase = col0 & 1023;
    #pragma unroll
    for (int j = 0; j < 4; ++j) {
        int cc = cbase + wn*64 + j*16 + lr;
        float bb = bias[cc];
        #pragma unroll
        for (int i = 0; i < 4; ++i) {
            int rg = row0 + wm*64 + i*16 + lk*4;
            #pragma unroll
            for (int r = 0; r < 4; ++r)
                O[(size_t)(rg + r)*1024 + cc] = f2bf(acc[i][j][r] + bb);
        }
    }
}

__global__ __launch_bounds__(256) void qk_gemm(
    const u16* __restrict__ Qb, const u16* __restrict__ Kb, float* __restrict__ S)
{
    __shared__ u16 As[128*64], Bs[128*64];
    const int tid = threadIdx.x;
    const int col0 = blockIdx.x*128, row0 = blockIdx.y*128, h = blockIdx.z;
    f32x4 acc[4][4] = {};
    gemm_bt_core<128>(Qb + (size_t)row0*1024 + h*64, 1024,
                      Kb + (size_t)col0*1024 + h*64, 1024, 64, As, Bs, acc, tid);
    const int l = tid & 63, wm = tid>>7, wn = (tid>>6)&1, lr = l&15, lk = l>>4;
    float* So = S + ((size_t)h << 20);
    #pragma unroll
    for (int j = 0; j < 4; ++j) {
        int cg = col0 + wn*64 + j*16 + lr;
        #pragma unroll
        for (int i = 0; i < 4; ++i) {
            int rg = row0 + wm*64 + i*16 + lk*4;
            #pragma unroll
            for (int r = 0; r < 4; ++r)
                So[(size_t)(rg + r)*1024 + cg] = acc[i][j][r] * SCALE;
        }
    }
}

__global__ __launch_bounds__(256) void pv_gemm(
    const u16* __restrict__ P, const u16* __restrict__ Vt, u16* __restrict__ AO)
{
    __shared__ u16 As[128*64], Bs[64*64];
    const int tid = threadIdx.x;
    const int row0 = blockIdx.x * 128, h = blockIdx.y;
    f32x4 acc[4][2] = {};
    gemm_bt_core<64>(P + ((size_t)((h<<10) + row0)) * 2048, 2048,
                     Vt + (size_t)h*64*1024, 1024, 1024, As, Bs, acc, tid);
    const int l = tid & 63, wm = tid>>7, wn = (tid>>6)&1, lr = l&15, lk = l>>4;
    #pragma unroll
    for (int j = 0; j < 2; ++j) {
        int col = h*64 + wn*32 + j*16 + lr;
        #pragma unroll
        for (int i = 0; i < 4; ++i) {
            int rg = row0 + wm*64 + i*16 + lk*4;
            #pragma unroll
            for (int r = 0; r < 4; ++r)
                AO[(size_t)(rg + r)*1024 + col] = f2bf(acc[i][j][r]);
        }
    }
}

__global__ __launch_bounds__(256) void out_gemm(
    const u16* __restrict__ AO, const u16* __restrict__ Wot,
    const float* __restrict__ bo, float* __restrict__ out)
{
    __shared__ u16 As[128*64], Bs[128*64];
    const int tid = threadIdx.x;
    const int col0 = blockIdx.x * 128, row0 = blockIdx.y * 128;
    f32x4 acc[4][4] = {};
    gemm_bt_core<128>(AO + (size_t)row0*1024, 1024,
                      Wot + (size_t)col0*1024, 1024, 1024, As, Bs, acc, tid);
    const int l = tid & 63, wm = tid>>7, wn = (tid>>6)&1, lr = l&15, lk = l>>4;
    #pragma unroll
    for (int j = 0; j < 4; ++j) {
        int cg = col0 + wn*64 + j*16 + lr;
        float bb = bo[cg];
        #pragma unroll
        for (int i = 0; i < 4; ++i) {
            int rg = row0 + wm*64 + i*16 + lk*4;
            #pragma unroll
            for (int r = 0; r < 4; ++r)
                out[(size_t)(rg + r)*1024 + cg] = acc[i][j][r] + bb;
        }
    }
}

// ---------------------------------------------------------------
// bias (spatial + edge enc) + mask + softmax over keys; reads fp32
// score rows, writes bf16 attn into the row's first half (in-place).
// ---------------------------------------------------------------
__global__ __launch_bounds__(512) void bias_softmax_kernel(
    const int* __restrict__ SD, const int* __restrict__ SP,
    const float* __restrict__ C, const float* __restrict__ STBL,
    float* __restrict__ S)
{
    __shared__ int   sdl[1024];
    __shared__ int   spl[4096];
    __shared__ float stbl[80];
    __shared__ float bias[4][1024];
    __shared__ float red[8];
    const int t = threadIdx.x;
    const int n = blockIdx.x;
    #pragma unroll
    for (int k = 0; k < 2; ++k) sdl[t + k*512] = SD[(size_t)n*1024 + t + k*512];
    #pragma unroll
    for (int k = 0; k < 2; ++k) {
        int4 v = *(const int4*)&SP[((size_t)n*1024 + t + k*512)*4];
        *(int4*)&spl[(t + k*512)*4] = v;
    }
    if (t < 80) stbl[t] = STBL[t];
    __syncthreads();

    for (int hc = 0; hc < 16; hc += 4) {
        if (hc) __syncthreads();
        #pragma unroll
        for (int k = 0; k < 2; ++k) {
            int m   = t + k*512;
            int sdv = sdl[m];
            int cl  = sdv > 4 ? 4 : (sdv < 0 ? 0 : sdv);
            float4 b  = *(const float4*)&stbl[cl*16 + hc];
            int4   e4 = *(const int4*)&spl[m*4];
            float4 c0 = *(const float4*)&C[(size_t)e4.x*64 +  0 + hc];
            float4 c1 = *(const float4*)&C[(size_t)e4.y*64 + 16 + hc];
            float4 c2 = *(const float4*)&C[(size_t)e4.z*64 + 32 + hc];
            float4 c3 = *(const float4*)&C[(size_t)e4.w*64 + 48 + hc];
            bias[0][m] = b.x + c0.x + c1.x + c2.x + c3.x;
            bias[1][m] = b.y + c0.y + c1.y + c2.y + c3.y;
            bias[2][m] = b.z + c0.z + c1.z + c2.z + c3.z;
            bias[3][m] = b.w + c0.w + c1.w + c2.w + c3.w;
        }
        __syncthreads();
        for (int hh = 0; hh < 4; ++hh) {
            const int h = hc + hh;
            float* srow = S + (((size_t)h << 10) + n) * 1024;
            float v[2];
            float lmax = -INFINITY;
            #pragma unroll
            for (int k = 0; k < 2; ++k) {
                int m = t + k*512;
                float x = (sdl[m] <= 0) ? -INFINITY : srow[m] + bias[hh][m];
                v[k] = x;
                lmax = fmaxf(lmax, x);
            }
            #pragma unroll
            for (int o = 32; o; o >>= 1) lmax = fmaxf(lmax, __shfl_xor(lmax, o));
            if ((t & 63) == 0) red[t >> 6] = lmax;
            __syncthreads();
            lmax = red[0];
            #pragma unroll
            for (int q = 1; q < 8; ++q) lmax = fmaxf(lmax, red[q]);
            __syncthreads();
            float lsum = 0.f;
            #pragma unroll
            for (int k = 0; k < 2; ++k) { v[k] = __expf(v[k] - lmax); lsum += v[k]; }
            #pragma unroll
            for (int o = 32; o; o >>= 1) lsum += __shfl_xor(lsum, o);
            if ((t & 63) == 0) red[t >> 6] = lsum;
            __syncthreads();
            lsum = red[0]+red[1]+red[2]+red[3]+red[4]+red[5]+red[6]+red[7];
            __syncthreads();
            float inv = 1.f / lsum;
            u16* prow = (u16*)srow;
            #pragma unroll
            for (int k = 0; k < 2; ++k) prow[t + k*512] = f2bf(v[k] * inv);
        }
    }
}

// ---------------------------------------------------------------
extern "C" void kernel_launch(void* const* d_in, const int* in_sizes, int n_in,
                              void* d_out, int out_size, void* d_ws, size_t ws_size,
                              hipStream_t stream)
{
    const float* node_feat = (const float*)d_in[0];
    const float* edge_feat = (const float*)d_in[1];
    const int*   sd        = (const int*)d_in[3];
    const int*   sp        = (const int*)d_in[4];
    const float* Wq = (const float*)d_in[6];
    const float* bq = (const float*)d_in[7];
    const float* Wk = (const float*)d_in[8];
    const float* bk = (const float*)d_in[9];
    const float* Wv = (const float*)d_in[10];
    const float* bv = (const float*)d_in[11];
    const float* Wo = (const float*)d_in[12];
    const float* bo = (const float*)d_in[13];
    const float* spatial = (const float*)d_in[14];
    const float* ew      = (const float*)d_in[15];
    float* out = (float*)d_out;

    char* base = (char*)d_ws;
    u16*   Xb = (u16*)(base);                           // 2MB (later Vt)
    u16*   Qb = (u16*)(base + ((size_t)2 << 20));       // 2MB (later attnout)
    u16*   Kb = (u16*)(base + ((size_t)4 << 20));       // 2MB
    u16*   Vb = (u16*)(base + ((size_t)6 << 20));       // 2MB
    u16*   Wt = (u16*)(base + ((size_t)8 << 20));       // 8MB (Wq,Wk,Wv,Wo transposed)
    float* C  = (float*)(base + ((size_t)16 << 20));    // 4,194,560 B
    float* S  = (float*)(base + ((size_t)16 << 20) + 4194560);  // 64MB
    u16*   Vt = Xb;   // alias: Xb dead after qkv_gemm
    u16*   AO = Qb;   // alias: Qb dead after qk_gemm

    conv_x<<<512, 256, 0, stream>>>(node_feat, Xb);
    conv_wt<<<dim3(16,16,4), 256, 0, stream>>>(Wq, Wk, Wv, Wo, Wt);
    edge_pre_kernel<<<dim3(E_/16 + 1), 256, 0, stream>>>(edge_feat, ew, C);
    qkv_gemm<<<dim3(24,8), 256, 0, stream>>>(Xb, Wt, bq, bk, bv, Qb, Kb, Vb);
    transpose_v<<<dim3(16,16), 256, 0, stream>>>(Vb, Vt);
    qk_gemm<<<dim3(8,8,16), 256, 0, stream>>>(Qb, Kb, S);
    bias_softmax_kernel<<<dim3(1024), 512, 0, stream>>>(sd, sp, C, spatial, S);
    pv_gemm<<<dim3(8,16), 256, 0, stream>>>((const u16*)S, Vt, AO);
    out_gemm<<<dim3(8,8), 256, 0, stream>>>(AO, Wt + (size_t)3*1024*1024, bo, out);
}

// Round 4
// 170.457 us; speedup vs baseline: 2.1377x; 1.2055x over previous
//
#include <hip/hip_runtime.h>
#include <math.h>

#define N_    1024
#define H_    16
#define E_    16384
#define SCALE 0.125f

typedef unsigned short u16;
typedef unsigned int   u32;
typedef short  short8v __attribute__((ext_vector_type(8)));
typedef float  f32x4   __attribute__((ext_vector_type(4)));
typedef u16    u16x4   __attribute__((ext_vector_type(4)));
typedef u16    u16x8   __attribute__((ext_vector_type(8)));

__device__ __forceinline__ u16 f2bf(float f) {
    union { float f; unsigned u; } v; v.f = f;
    unsigned r = v.u + 0x7fffu + ((v.u >> 16) & 1u);
    return (u16)(r >> 16);
}

// ---------------------------------------------------------------
// staging: global(bf16, row-major, ld=ldr) -> LDS tile [rows][64]
// XOR slot swizzle applied on the GLOBAL source (linear LDS dest).
// ---------------------------------------------------------------
template<int U64>
__device__ __forceinline__ void stage_bt(const u16* __restrict__ g, int ldr,
                                         u16* s, int tid)
{
    const int l = tid & 63, w = tid >> 6;
    for (int c = w; c < U64; c += 4) {
        int o16 = (c << 6) + l;
        int row = o16 >> 3;
        int ss  = (o16 & 7) ^ (row & 7);
        const u16* gp = g + (size_t)row * ldr + (ss << 3);
        u16* lp = s + (c << 9);
        __builtin_amdgcn_global_load_lds(
            (const __attribute__((address_space(1))) void*)gp,
            (__attribute__((address_space(3))) void*)lp, 16, 0, 0);
    }
}

__device__ __forceinline__ short8v frag_read(const u16* s, int row, int slot) {
    return *(const short8v*)(s + row * 64 + ((slot ^ (row & 7)) << 3));
}

// ---------------------------------------------------------------
// bf16 GEMM-BT core: block tile 128 x NT, 4 waves (2x2), BK=64.
// ---------------------------------------------------------------
template<int NT>
__device__ __forceinline__ void gemm_bt_core(
    const u16* __restrict__ At, int lda,
    const u16* __restrict__ Bt, int ldb,
    int K, u16* As, u16* Bs, f32x4 (&acc)[4][NT/32], int tid)
{
    const int l  = tid & 63;
    const int wm = tid >> 7, wn = (tid >> 6) & 1;
    const int lr = l & 15,   lk = l >> 4;
    for (int k0 = 0; k0 < K; k0 += 64) {
        if (k0) __syncthreads();
        stage_bt<16>(At + k0, lda, As, tid);
        stage_bt<NT/8>(Bt + k0, ldb, Bs, tid);
        __syncthreads();
        #pragma unroll
        for (int s = 0; s < 2; ++s) {
            short8v af[4], bfv[NT/32];
            #pragma unroll
            for (int i = 0; i < 4; ++i)
                af[i] = frag_read(As, wm*64 + i*16 + lr, s*4 + lk);
            #pragma unroll
            for (int j = 0; j < NT/32; ++j)
                bfv[j] = frag_read(Bs, wn*(NT/2) + j*16 + lr, s*4 + lk);
            #pragma unroll
            for (int i = 0; i < 4; ++i)
                #pragma unroll
                for (int j = 0; j < NT/32; ++j)
                    asm("v_mfma_f32_16x16x32_bf16 %0, %1, %2, %0"
                        : "+v"(acc[i][j]) : "v"(af[i]), "v"(bfv[j]));
        }
    }
    __syncthreads();
}

// ---------------------------------------------------------------
// converts
// ---------------------------------------------------------------
__global__ __launch_bounds__(256) void conv_x(const float* __restrict__ X,
                                              u16* __restrict__ Xb)
{
    size_t i = (size_t)blockIdx.x * 256 + threadIdx.x;
    float4 a = ((const float4*)X)[2*i], b = ((const float4*)X)[2*i + 1];
    u16x8 o;
    o[0]=f2bf(a.x); o[1]=f2bf(a.y); o[2]=f2bf(a.z); o[3]=f2bf(a.w);
    o[4]=f2bf(b.x); o[5]=f2bf(b.y); o[6]=f2bf(b.z); o[7]=f2bf(b.w);
    *(u16x8*)&Xb[8*i] = o;
}

__global__ __launch_bounds__(256) void conv_wt(
    const float* __restrict__ Wq, const float* __restrict__ Wk,
    const float* __restrict__ Wv, const float* __restrict__ Wo,
    u16* __restrict__ Wt)
{
    __shared__ u16 tile[64][65];
    const int t = threadIdx.x;
    const int n0 = blockIdx.x*64, k0 = blockIdx.y*64, mz = blockIdx.z;
    const float* W = mz==0 ? Wq : mz==1 ? Wk : mz==2 ? Wv : Wo;
    u16* Wd = Wt + (size_t)mz * 1024 * 1024;
    #pragma unroll
    for (int p = 0; p < 4; ++p) {
        int r = p*16 + (t>>4), c = (t&15)*4;
        float4 v = *(const float4*)&W[(size_t)(k0+r)*1024 + n0 + c];
        tile[c+0][r]=f2bf(v.x); tile[c+1][r]=f2bf(v.y);
        tile[c+2][r]=f2bf(v.z); tile[c+3][r]=f2bf(v.w);
    }
    __syncthreads();
    #pragma unroll
    for (int p = 0; p < 4; ++p) {
        int nr = p*16 + (t>>4), kc = (t&15)*4;
        u16x4 o = { tile[nr][kc], tile[nr][kc+1], tile[nr][kc+2], tile[nr][kc+3] };
        *(u16x4*)&Wd[(size_t)(n0+nr)*1024 + k0 + kc] = o;
    }
}

__global__ __launch_bounds__(256) void transpose_v(const u16* __restrict__ Vb,
                                                   u16* __restrict__ Vt)
{
    __shared__ u16 tile[64][65];
    const int t = threadIdx.x;
    const int c0 = blockIdx.x*64, r0 = blockIdx.y*64;
    #pragma unroll
    for (int p = 0; p < 4; ++p) {
        int r = p*16 + (t>>4), c = (t&15)*4;
        u16x4 v = *(const u16x4*)&Vb[(size_t)(r0+r)*1024 + c0 + c];
        tile[c+0][r]=v[0]; tile[c+1][r]=v[1]; tile[c+2][r]=v[2]; tile[c+3][r]=v[3];
    }
    __syncthreads();
    #pragma unroll
    for (int p = 0; p < 4; ++p) {
        int cr = p*16 + (t>>4), rc = (t&15)*4;
        u16x4 o = { tile[cr][rc], tile[cr][rc+1], tile[cr][rc+2], tile[cr][rc+3] };
        *(u16x4*)&Vt[(size_t)(c0+cr)*1024 + r0 + rc] = o;
    }
}

// ---------------------------------------------------------------
// C[e][l][h] = dot(edge_feat[e], edge_weight[l][h]) ; row E = 0
// ---------------------------------------------------------------
__global__ __launch_bounds__(256) void edge_pre_kernel(
    const float* __restrict__ EF, const float* __restrict__ EW, float* __restrict__ C)
{
    __shared__ float ews[64][66];
    __shared__ float ef[16][64];
    const int t = threadIdx.x;
    const int e0 = blockIdx.x * 16;
    #pragma unroll
    for (int i = 0; i < 16; ++i) {
        int idx = t + i * 256;
        ews[idx >> 6][idx & 63] = EW[idx];
    }
    #pragma unroll
    for (int i = 0; i < 4; ++i) {
        int idx = t + i * 256;
        int r = idx >> 6, d = idx & 63;
        int e = e0 + r;
        ef[r][d] = (e < E_) ? EF[(size_t)e * 64 + d] : 0.f;
    }
    __syncthreads();
    const int lh = t & 63;
    const int rb = t >> 6;
    #pragma unroll
    for (int j = 0; j < 4; ++j) {
        int r = rb * 4 + j;
        int e = e0 + r;
        if (e > E_) continue;
        float acc = 0.f;
        if (e < E_) {
            #pragma unroll
            for (int d = 0; d < 64; ++d) acc += ef[r][d] * ews[lh][d];
        }
        C[(size_t)e * 64 + lh] = acc;
    }
}

// ---------------------------------------------------------------
// GEMM kernels
// ---------------------------------------------------------------
__global__ __launch_bounds__(256) void qkv_gemm(
    const u16* __restrict__ Xb, const u16* __restrict__ Wt,
    const float* __restrict__ bq, const float* __restrict__ bk,
    const float* __restrict__ bv,
    u16* __restrict__ Qb, u16* __restrict__ Kb, u16* __restrict__ Vb)
{
    __shared__ u16 As[128*64], Bs[128*64];
    const int tid = threadIdx.x;
    const int col0 = blockIdx.x * 128, row0 = blockIdx.y * 128;
    f32x4 acc[4][4] = {};
    gemm_bt_core<128>(Xb + (size_t)row0*1024, 1024,
                      Wt + (size_t)col0*1024, 1024, 1024, As, Bs, acc, tid);
    const int l = tid & 63, wm = tid>>7, wn = (tid>>6)&1, lr = l&15, lk = l>>4;
    const int sel = col0 >> 10;
    const float* bias = sel==0 ? bq : sel==1 ? bk : bv;
    u16* O = sel==0 ? Qb : sel==1 ? Kb : Vb;
    const int cbase = col0 & 1023;
    #pragma unroll
    for (int j = 0; j < 4; ++j) {
        int cc = cbase + wn*64 + j*16 + lr;
        float bb = bias[cc];
        #pragma unroll
        for (int i = 0; i < 4; ++i) {
            int rg = row0 + wm*64 + i*16 + lk*4;
            #pragma unroll
            for (int r = 0; r < 4; ++r)
                O[(size_t)(rg + r)*1024 + cc] = f2bf(acc[i][j][r] + bb);
        }
    }
}

__global__ __launch_bounds__(256) void qk_gemm(
    const u16* __restrict__ Qb, const u16* __restrict__ Kb, float* __restrict__ S)
{
    __shared__ u16 As[128*64], Bs[128*64];
    const int tid = threadIdx.x;
    const int col0 = blockIdx.x*128, row0 = blockIdx.y*128, h = blockIdx.z;
    f32x4 acc[4][4] = {};
    gemm_bt_core<128>(Qb + (size_t)row0*1024 + h*64, 1024,
                      Kb + (size_t)col0*1024 + h*64, 1024, 64, As, Bs, acc, tid);
    const int l = tid & 63, wm = tid>>7, wn = (tid>>6)&1, lr = l&15, lk = l>>4;
    float* So = S + ((size_t)h << 20);
    #pragma unroll
    for (int j = 0; j < 4; ++j) {
        int cg = col0 + wn*64 + j*16 + lr;
        #pragma unroll
        for (int i = 0; i < 4; ++i) {
            int rg = row0 + wm*64 + i*16 + lk*4;
            #pragma unroll
            for (int r = 0; r < 4; ++r)
                So[(size_t)(rg + r)*1024 + cg] = acc[i][j][r] * SCALE;
        }
    }
}

__global__ __launch_bounds__(256) void pv_gemm(
    const u16* __restrict__ P, const u16* __restrict__ Vt, u16* __restrict__ AO)
{
    __shared__ u16 As[128*64], Bs[64*64];
    const int tid = threadIdx.x;
    const int row0 = blockIdx.x * 128, h = blockIdx.y;
    f32x4 acc[4][2] = {};
    gemm_bt_core<64>(P + ((size_t)((h<<10) + row0)) * 2048, 2048,
                     Vt + (size_t)h*64*1024, 1024, 1024, As, Bs, acc, tid);
    const int l = tid & 63, wm = tid>>7, wn = (tid>>6)&1, lr = l&15, lk = l>>4;
    #pragma unroll
    for (int j = 0; j < 2; ++j) {
        int col = h*64 + wn*32 + j*16 + lr;
        #pragma unroll
        for (int i = 0; i < 4; ++i) {
            int rg = row0 + wm*64 + i*16 + lk*4;
            #pragma unroll
            for (int r = 0; r < 4; ++r)
                AO[(size_t)(rg + r)*1024 + col] = f2bf(acc[i][j][r]);
        }
    }
}

__global__ __launch_bounds__(256) void out_gemm(
    const u16* __restrict__ AO, const u16* __restrict__ Wot,
    const float* __restrict__ bo, float* __restrict__ out)
{
    __shared__ u16 As[128*64], Bs[128*64];
    const int tid = threadIdx.x;
    const int col0 = blockIdx.x * 128, row0 = blockIdx.y * 128;
    f32x4 acc[4][4] = {};
    gemm_bt_core<128>(AO + (size_t)row0*1024, 1024,
                      Wot + (size_t)col0*1024, 1024, 1024, As, Bs, acc, tid);
    const int l = tid & 63, wm = tid>>7, wn = (tid>>6)&1, lr = l&15, lk = l>>4;
    #pragma unroll
    for (int j = 0; j < 4; ++j) {
        int cg = col0 + wn*64 + j*16 + lr;
        float bb = bo[cg];
        #pragma unroll
        for (int i = 0; i < 4; ++i) {
            int rg = row0 + wm*64 + i*16 + lk*4;
            #pragma unroll
            for (int r = 0; r < 4; ++r)
                out[(size_t)(rg + r)*1024 + cg] = acc[i][j][r] + bb;
        }
    }
}

// ---------------------------------------------------------------
// bias (spatial + edge enc) + mask + softmax; S is fp32 [h][n][m].
// 8 waves; each wave owns one full head row. bf16 probs are packed
// into the first 1024 u16 of each fp32 row (stride 2048 for pv).
// ---------------------------------------------------------------
__global__ __launch_bounds__(512) void bias_softmax2(
    const int* __restrict__ SD, const int* __restrict__ SP,
    const float* __restrict__ C, const float* __restrict__ STBL,
    float* __restrict__ S)
{
    __shared__ int   sdl[1024];
    __shared__ int   sp0[1024], sp1[1024], sp2[1024], sp3[1024];
    __shared__ float stbl[80];
    __shared__ float bias[8][1024];
    const int t = threadIdx.x;
    const int n = blockIdx.x;
    #pragma unroll
    for (int k = 0; k < 2; ++k) {
        int m = t + k*512;
        sdl[m] = SD[(size_t)n*1024 + m];
        int4 v = *(const int4*)&SP[((size_t)n*1024 + m)*4];
        sp0[m] = v.x; sp1[m] = v.y; sp2[m] = v.z; sp3[m] = v.w;
    }
    if (t < 80) stbl[t] = STBL[t];
    __syncthreads();

    const int w = t >> 6, lane = t & 63;
    for (int hc = 0; hc < 16; hc += 8) {
        if (hc) __syncthreads();
        #pragma unroll
        for (int k = 0; k < 2; ++k) {
            int m = t + k*512;
            int sdv = sdl[m];
            int cl  = sdv > 4 ? 4 : (sdv < 0 ? 0 : sdv);
            float4 b0 = *(const float4*)&stbl[cl*16 + hc];
            float4 b1 = *(const float4*)&stbl[cl*16 + hc + 4];
            const float* c0 = &C[(size_t)sp0[m]*64 +  0 + hc];
            const float* c1 = &C[(size_t)sp1[m]*64 + 16 + hc];
            const float* c2 = &C[(size_t)sp2[m]*64 + 32 + hc];
            const float* c3 = &C[(size_t)sp3[m]*64 + 48 + hc];
            float4 a0 = *(const float4*)c0, a1 = *(const float4*)(c0 + 4);
            float4 d0 = *(const float4*)c1, d1 = *(const float4*)(c1 + 4);
            float4 f0 = *(const float4*)c2, f1 = *(const float4*)(c2 + 4);
            float4 g0 = *(const float4*)c3, g1 = *(const float4*)(c3 + 4);
            bias[0][m] = b0.x + a0.x + d0.x + f0.x + g0.x;
            bias[1][m] = b0.y + a0.y + d0.y + f0.y + g0.y;
            bias[2][m] = b0.z + a0.z + d0.z + f0.z + g0.z;
            bias[3][m] = b0.w + a0.w + d0.w + f0.w + g0.w;
            bias[4][m] = b1.x + a1.x + d1.x + f1.x + g1.x;
            bias[5][m] = b1.y + a1.y + d1.y + f1.y + g1.y;
            bias[6][m] = b1.z + a1.z + d1.z + f1.z + g1.z;
            bias[7][m] = b1.w + a1.w + d1.w + f1.w + g1.w;
        }
        __syncthreads();
        const int h = hc + w;
        float* srow = S + (((size_t)h << 10) + n) * 1024;
        float v[16];
        float lmax = -INFINITY;
        #pragma unroll
        for (int j = 0; j < 8; ++j) {
            int m = lane*2 + j*128;
            float2 sv = *(const float2*)&srow[m];
            float2 bb = *(const float2*)&bias[w][m];
            int2 sd2 = *(const int2*)&sdl[m];
            float x0 = (sd2.x <= 0) ? -INFINITY : sv.x + bb.x;
            float x1 = (sd2.y <= 0) ? -INFINITY : sv.y + bb.y;
            v[2*j] = x0; v[2*j+1] = x1;
            lmax = fmaxf(lmax, fmaxf(x0, x1));
        }
        #pragma unroll
        for (int o = 32; o; o >>= 1) lmax = fmaxf(lmax, __shfl_xor(lmax, o));
        float lsum = 0.f;
        #pragma unroll
        for (int j = 0; j < 16; ++j) { v[j] = __expf(v[j] - lmax); lsum += v[j]; }
        #pragma unroll
        for (int o = 32; o; o >>= 1) lsum += __shfl_xor(lsum, o);
        float inv = 1.f / lsum;
        u16* prow = (u16*)srow;
        #pragma unroll
        for (int j = 0; j < 8; ++j) {
            int m = lane*2 + j*128;
            u32 pk = ((u32)f2bf(v[2*j+1] * inv) << 16) | f2bf(v[2*j] * inv);
            *(u32*)&prow[m] = pk;
        }
    }
}

// ---------------------------------------------------------------
extern "C" void kernel_launch(void* const* d_in, const int* in_sizes, int n_in,
                              void* d_out, int out_size, void* d_ws, size_t ws_size,
                              hipStream_t stream)
{
    const float* node_feat = (const float*)d_in[0];
    const float* edge_feat = (const float*)d_in[1];
    const int*   sd        = (const int*)d_in[3];
    const int*   sp        = (const int*)d_in[4];
    const float* Wq = (const float*)d_in[6];
    const float* bq = (const float*)d_in[7];
    const float* Wk = (const float*)d_in[8];
    const float* bk = (const float*)d_in[9];
    const float* Wv = (const float*)d_in[10];
    const float* bv = (const float*)d_in[11];
    const float* Wo = (const float*)d_in[12];
    const float* bo = (const float*)d_in[13];
    const float* spatial = (const float*)d_in[14];
    const float* ew      = (const float*)d_in[15];
    float* out = (float*)d_out;

    char* base = (char*)d_ws;
    u16*   Xb = (u16*)(base);                           // 2MB (later Vt)
    u16*   Qb = (u16*)(base + ((size_t)2 << 20));       // 2MB (later attnout)
    u16*   Kb = (u16*)(base + ((size_t)4 << 20));       // 2MB
    u16*   Vb = (u16*)(base + ((size_t)6 << 20));       // 2MB
    u16*   Wt = (u16*)(base + ((size_t)8 << 20));       // 8MB
    float* C  = (float*)(base + ((size_t)16 << 20));    // 4,194,560 B
    float* S  = (float*)(base + ((size_t)16 << 20) + 4194560);  // 64MB fp32
    u16*   Vt = Xb;   // alias: Xb dead after qkv_gemm
    u16*   AO = Qb;   // alias: Qb dead after qk_gemm

    conv_x<<<512, 256, 0, stream>>>(node_feat, Xb);
    conv_wt<<<dim3(16,16,4), 256, 0, stream>>>(Wq, Wk, Wv, Wo, Wt);
    edge_pre_kernel<<<dim3(E_/16 + 1), 256, 0, stream>>>(edge_feat, ew, C);
    qkv_gemm<<<dim3(24,8), 256, 0, stream>>>(Xb, Wt, bq, bk, bv, Qb, Kb, Vb);
    transpose_v<<<dim3(16,16), 256, 0, stream>>>(Vb, Vt);
    qk_gemm<<<dim3(8,8,16), 256, 0, stream>>>(Qb, Kb, S);
    bias_softmax2<<<dim3(1024), 512, 0, stream>>>(sd, sp, C, spatial, S);
    pv_gemm<<<dim3(8,16), 256, 0, stream>>>((const u16*)S, Vt, AO);
    out_gemm<<<dim3(8,8), 256, 0, stream>>>(AO, Wt + (size_t)3*1024*1024, bo, out);
}